// Round 1
// baseline (1605.492 us; speedup 1.0000x reference)
//
#include <hip/hip_runtime.h>

// Q8Linear: out[t][o] = (sum_k x[t][k]*w[o][k]) * xs[t] * ws[o] + bias[o]
// T=8192, K=4096, O=16384. Exact int32 accumulation via mfma_i32_16x16x64_i8.
//
// Phase 1: pack int32-valued int8 inputs to real int8 in d_ws (96 MiB).
// Phase 2: 256x256-tile i8 MFMA GEMM, 8-phase-style counted-vmcnt pipeline:
//   - 512 threads = 8 waves (2M x 4N), per-wave 128x64 output (8x4 acc frags)
//   - BK=64, 4-deep LDS ring per matrix (4 x 16KB x 2 = 128 KiB LDS)
//   - staging runs 3 K-tiles ahead; per-tile checkpoint s_waitcnt vmcnt(6)
//     (never vmcnt(0) in the main loop); raw s_barrier (no syncthreads drain)
//   - XOR-swizzled LDS (slot ^= blk&7, 16B granularity) -> conflict-free
//     ds_read_b128; global source is pre-swizzled so global_load_lds's linear
//     wave-uniform destination still lands data at the swizzled spot
//   - s_setprio(1) around each 16-MFMA cluster; XCD-aware block swizzle

#define T_DIM 8192
#define K_DIM 4096
#define N_DIM 16384

typedef __attribute__((ext_vector_type(4))) int int4v;

__global__ __launch_bounds__(256) void pack_i8(const int4v* __restrict__ src,
                                               int* __restrict__ dst) {
  const int idx = blockIdx.x * 256 + threadIdx.x;
  int4v v = src[idx];
  dst[idx] = (v.x & 255) | ((v.y & 255) << 8) | ((v.z & 255) << 16) | (v.w << 24);
}

__device__ __forceinline__ void gll16(const char* g, char* l) {
  __builtin_amdgcn_global_load_lds(
      (const __attribute__((address_space(1))) void*)g,
      (__attribute__((address_space(3))) void*)l, 16, 0, 0);
}

#define MFMA_ROW(M, AF)                                                          \
  acc[M][0] = __builtin_amdgcn_mfma_i32_16x16x64_i8(AF, b0, acc[M][0], 0, 0, 0); \
  acc[M][1] = __builtin_amdgcn_mfma_i32_16x16x64_i8(AF, b1, acc[M][1], 0, 0, 0); \
  acc[M][2] = __builtin_amdgcn_mfma_i32_16x16x64_i8(AF, b2, acc[M][2], 0, 0, 0); \
  acc[M][3] = __builtin_amdgcn_mfma_i32_16x16x64_i8(AF, b3, acc[M][3], 0, 0, 0);

#define VMW6 asm volatile("s_waitcnt vmcnt(6)" ::: "memory")
#define VMW4 asm volatile("s_waitcnt vmcnt(4)" ::: "memory")
#define VMW0 asm volatile("s_waitcnt vmcnt(0)" ::: "memory")

// Tile body: tile KT reads buf KT&3; stages tile KT+3 into buf (KT+3)&3.
// Phase 1 checkpoint confirms tile KT+1's loads landed (issued 2 tiles ago),
// then the barrier publishes that to all waves before tile KT+1 is read.
#define TILE_BODY(KT, VMW, ST)                                                 \
  do {                                                                         \
    const int rbuf = (KT) & 3;                                                 \
    const char* pa = &lA[rbuf][0] + aoff0;                                     \
    const char* pb = &lB[rbuf][0] + boff0;                                     \
    /* ---- phase 1: stage A(kt+3) | read A0-3,B0-3 | 16 MFMA ---- */          \
    if (ST) {                                                                  \
      const int sbuf = ((KT) + 3) & 3;                                         \
      const size_t kc = (size_t)((KT) + 3) * 64;                               \
      char* da = &lA[sbuf][tido];                                              \
      gll16(sa + kc, da);                                                      \
      gll16(sa + kc + (size_t)128 * K_DIM, da + 8192);                         \
    }                                                                          \
    VMW;                                                                       \
    int4v a0 = *(const int4v*)(pa);                                            \
    int4v a1 = *(const int4v*)(pa + 1024);                                     \
    int4v a2 = *(const int4v*)(pa + 2048);                                     \
    int4v a3 = *(const int4v*)(pa + 3072);                                     \
    int4v b0 = *(const int4v*)(pb);                                            \
    int4v b1 = *(const int4v*)(pb + 1024);                                     \
    int4v b2 = *(const int4v*)(pb + 2048);                                     \
    int4v b3 = *(const int4v*)(pb + 3072);                                     \
    __builtin_amdgcn_s_barrier();                                              \
    asm volatile("s_waitcnt lgkmcnt(0)" ::: "memory");                         \
    __builtin_amdgcn_sched_barrier(0);                                         \
    __builtin_amdgcn_s_setprio(1);                                             \
    MFMA_ROW(0, a0) MFMA_ROW(1, a1) MFMA_ROW(2, a2) MFMA_ROW(3, a3)            \
    __builtin_amdgcn_s_setprio(0);                                             \
    __builtin_amdgcn_s_barrier();                                              \
    /* ---- phase 2: stage B(kt+3) | read A4-7 | 16 MFMA ---- */               \
    if (ST) {                                                                  \
      const int sbuf = ((KT) + 3) & 3;                                         \
      const size_t kc = (size_t)((KT) + 3) * 64;                               \
      char* db = &lB[sbuf][tido];                                              \
      gll16(sb + kc, db);                                                      \
      gll16(sb + kc + (size_t)128 * K_DIM, db + 8192);                         \
    }                                                                          \
    int4v a4 = *(const int4v*)(pa + 4096);                                     \
    int4v a5 = *(const int4v*)(pa + 5120);                                     \
    int4v a6 = *(const int4v*)(pa + 6144);                                     \
    int4v a7 = *(const int4v*)(pa + 7168);                                     \
    __builtin_amdgcn_s_barrier();                                              \
    asm volatile("s_waitcnt lgkmcnt(0)" ::: "memory");                         \
    __builtin_amdgcn_sched_barrier(0);                                         \
    __builtin_amdgcn_s_setprio(1);                                             \
    MFMA_ROW(4, a4) MFMA_ROW(5, a5) MFMA_ROW(6, a6) MFMA_ROW(7, a7)            \
    __builtin_amdgcn_s_setprio(0);                                             \
    __builtin_amdgcn_s_barrier();                                              \
  } while (0)

__global__ __launch_bounds__(512, 2) void gemm_i8(
    const char* __restrict__ A8,        // [T_DIM][K_DIM] int8
    const char* __restrict__ B8,        // [N_DIM][K_DIM] int8 (o-major)
    const float* __restrict__ xscale,   // [T_DIM]
    const float* __restrict__ wscale,   // [N_DIM]
    const float* __restrict__ bias,     // [N_DIM]
    float* __restrict__ out) {          // [T_DIM][N_DIM] fp32
  // 4-deep ring, one 256x64 i8 tile (16KB) per slot per matrix = 128 KiB.
  __shared__ __align__(16) char lA[4][256 * 64];
  __shared__ __align__(16) char lB[4][256 * 64];

  const int tid = threadIdx.x;
  const int lane = tid & 63;
  const int wave = tid >> 6;
  const int mg = wave >> 2;  // 0..1 : M wave-group (128 rows each)
  const int ng = wave & 3;   // 0..3 : N wave-group (64 cols each)

  // XCD-aware swizzle: 2048 wg, 8 XCDs; XCD x owns bx in [8x,8x+8), by fastest
  // -> B-panel (1MB) L2-resident per XCD, A streams from L3 (A+B fit in L3).
  const int bid = blockIdx.x;
  const int bx = (bid & 7) * 8 + ((bid >> 3) >> 5);  // 0..63 (N blocks)
  const int by = (bid >> 3) & 31;                    // 0..31 (T blocks)
  const int blockM = by * 256;
  const int blockN = bx * 256;

  // Staging source (pre-swizzled): thread tid fills LDS bytes [tid*16,+16).
  // LDS layout: [row][64] i8, XOR-swizzled: 16B slot s at 128B-block blk holds
  // original slot s^(blk&7). deswz(tid*16): blk=tid>>3, s=tid&7.
  const int s2 = (tid & 7) ^ ((tid >> 3) & 7);
  const int r0 = ((tid >> 3) << 1) | (s2 >> 2);  // row within 128-row half
  const int c0 = (s2 & 3) << 4;                  // byte col within 64B row
  const int tido = tid << 4;
  const char* sa = A8 + (size_t)(blockM + r0) * K_DIM + c0;
  const char* sb = B8 + (size_t)(blockN + r0) * K_DIM + c0;

  // Fragment read offsets (swizzled). Row step of 16 -> +1024 bytes exactly
  // (blk&7 invariant), so frags use one base + immediate offsets.
  const int ln = lane & 15;
  const int q = lane >> 4;
  const int ra = mg * 128 + ln;
  const int rbrow = ng * 64 + ln;
  const int aoff0 =
      ((ra >> 1) << 7) | (((((ra & 1) << 2) | q) ^ ((ra >> 1) & 7)) << 4);
  const int boff0 =
      ((rbrow >> 1) << 7) | (((((rbrow & 1) << 2) | q) ^ ((rbrow >> 1) & 7)) << 4);

  int4v acc[8][4] = {};  // 128 VGPRs

  // Prologue: stage tiles 0,1,2 into ring slots 0,1,2; confirm tile 0 landed.
#pragma unroll
  for (int t = 0; t < 3; ++t) {
    const int kc = t * 64;
    char* da = &lA[t][tido];
    char* db = &lB[t][tido];
    gll16(sa + kc, da);
    gll16(sa + kc + (size_t)128 * K_DIM, da + 8192);
    gll16(sb + kc, db);
    gll16(sb + kc + (size_t)128 * K_DIM, db + 8192);
  }
  asm volatile("s_waitcnt vmcnt(8)" ::: "memory");  // tile0's 4 loads landed
  __builtin_amdgcn_s_barrier();

  // Main loop: 64 K-tiles. Steady state vmcnt(6); tail peels the checkpoints.
#pragma unroll 1
  for (int kt = 0; kt < 61; ++kt) {
    TILE_BODY(kt, VMW6, 1);
  }
  TILE_BODY(61, VMW4, 0);
  TILE_BODY(62, VMW0, 0);
  TILE_BODY(63, VMW0, 0);

  // Epilogue: C/D layout col=lane&15, row=q*4+reg (dtype-independent).
  const int row0 = blockM + mg * 128 + q * 4;
  const int col0 = blockN + ng * 64 + ln;
#pragma unroll
  for (int n = 0; n < 4; ++n) {
    const int o = col0 + n * 16;
    const float so = wscale[o];
    const float bo = bias[o];
#pragma unroll
    for (int m = 0; m < 8; ++m) {
      const int t = row0 + m * 16;
#pragma unroll
      for (int r = 0; r < 4; ++r) {
        out[(size_t)(t + r) * N_DIM + o] =
            (float)acc[m][n][r] * xscale[t + r] * so + bo;
      }
    }
  }
}

extern "C" void kernel_launch(void* const* d_in, const int* in_sizes, int n_in,
                              void* d_out, int out_size, void* d_ws, size_t ws_size,
                              hipStream_t stream) {
  const int* x = (const int*)d_in[0];       // [T_DIM][K_DIM] int32 (int8-valued)
  const int* w = (const int*)d_in[1];       // [N_DIM][K_DIM] int32 (int8-valued)
  const float* bias = (const float*)d_in[2];
  const float* xs = (const float*)d_in[3];
  const float* ws = (const float*)d_in[4];
  float* out = (float*)d_out;

  char* x8 = (char*)d_ws;                           // 32 MiB
  char* w8 = x8 + (size_t)T_DIM * K_DIM;            // 64 MiB

  pack_i8<<<(T_DIM * K_DIM) / 1024, 256, 0, stream>>>((const int4v*)x, (int*)x8);
  pack_i8<<<((size_t)N_DIM * K_DIM) / 1024, 256, 0, stream>>>((const int4v*)w, (int*)w8);

  gemm_i8<<<dim3(2048), 512, 0, stream>>>(x8, w8, xs, ws, bias, out);
}